// Round 1
// baseline (461.750 us; speedup 1.0000x reference)
//
#include <hip/hip_runtime.h>

#define NROWS 16384
#define D 4096
#define RPB 16          // rows per block
#define THREADS 256

// ---------- setup: inverse permutation ----------
__global__ void k_inv_perm(const int* __restrict__ perm, int* __restrict__ inv) {
    int d = blockIdx.x * blockDim.x + threadIdx.x;
    if (d < D) inv[perm[d]] = d;
}

// ---------- fused Tucker kernel ----------
__launch_bounds__(THREADS, 2)
__global__ void k_tucker(const float* __restrict__ x,
                         const float* __restrict__ core,
                         const float* __restrict__ fi0,
                         const float* __restrict__ fi1,
                         const float* __restrict__ fi2,
                         const float* __restrict__ fo0,
                         const float* __restrict__ fo1,
                         const float* __restrict__ fo2,
                         const float* __restrict__ pds,
                         const float* __restrict__ alpha_p,
                         const float* __restrict__ bias,
                         const int* __restrict__ inv,
                         float* __restrict__ out) {
    __shared__ float t3all[RPB][512];      // 32 KB
    __shared__ float scratch[7168];        // 28 KB, multi-purpose
    __shared__ float fac[6][128];          // 3 KB factors

    const int tid = threadIdx.x;
    const int n0 = blockIdx.x * RPB;

    if (tid < 128) {
        fac[0][tid] = fi0[tid];
        fac[1][tid] = fi1[tid];
        fac[2][tid] = fi2[tid];
        fac[3][tid] = fo0[tid];
        fac[4][tid] = fo1[tid];
        fac[5][tid] = fo2[tid];
    }

    float* xr = scratch;            // [4096]
    float* t1 = scratch + 4096;     // [2048]  t1[p][b*16+c] = p*256+bc
    float* t2 = scratch + 6144;     // [1024]  t2[p][q][c]   = p*128+q*16+c

    // preload inverse-perm indices this thread will use (reused for all rows)
    int4 ivs[4];
    #pragma unroll
    for (int it = 0; it < 4; ++it)
        ivs[it] = ((const int4*)inv)[tid + it * 256];

    // ---------------- Phase A: rows -> t3 ----------------
    for (int r = 0; r < RPB; ++r) {
        const int n = n0 + r;
        __syncthreads();   // protect xr reuse
        const float4* xrow = (const float4*)(x + (size_t)n * D);
        #pragma unroll
        for (int it = 0; it < 4; ++it) {
            float4 v = xrow[tid + it * 256];
            int4  iv = ivs[it];
            xr[iv.x] = v.x; xr[iv.y] = v.y; xr[iv.z] = v.z; xr[iv.w] = v.w;
        }
        __syncthreads();
        // step 3: t1[p,b,c] = sum_a xr[a,b,c] * fi0[a,p]
        {
            const int bc = tid;
            float a8[8] = {0,0,0,0,0,0,0,0};
            #pragma unroll
            for (int a = 0; a < 16; ++a) {
                float v = xr[a * 256 + bc];
                #pragma unroll
                for (int p = 0; p < 8; ++p) a8[p] += v * fac[0][a * 8 + p];
            }
            #pragma unroll
            for (int p = 0; p < 8; ++p) t1[p * 256 + bc] = a8[p];
        }
        __syncthreads();
        // step 4: t2[p,q,c] = sum_b t1[p,b,c] * fi1[b,q]
        if (tid < 128) {
            const int p = tid >> 4, c = tid & 15;
            float a8[8] = {0,0,0,0,0,0,0,0};
            #pragma unroll
            for (int b = 0; b < 16; ++b) {
                float v = t1[p * 256 + b * 16 + c];
                #pragma unroll
                for (int q = 0; q < 8; ++q) a8[q] += v * fac[1][b * 8 + q];
            }
            #pragma unroll
            for (int q = 0; q < 8; ++q) t2[p * 128 + q * 16 + c] = a8[q];
        }
        __syncthreads();
        // step 5: t3[p,q,rr] = sum_c t2[p,q,c] * fi2[c,rr]
        if (tid < 64) {
            const int p = tid >> 3, q = tid & 7;
            float a8[8] = {0,0,0,0,0,0,0,0};
            #pragma unroll
            for (int c = 0; c < 16; ++c) {
                float v = t2[p * 128 + q * 16 + c];
                #pragma unroll
                for (int rr = 0; rr < 8; ++rr) a8[rr] += v * fac[2][c * 8 + rr];
            }
            #pragma unroll
            for (int rr = 0; rr < 8; ++rr) t3all[r][p * 64 + q * 8 + rr] = a8[rr];
        }
    }
    __syncthreads();

    // ---------------- Core GEMM: t4[r][o] = sum_k t3[r][k] * core[o*512+k] ----
    // thread owns o0 = tid, o1 = tid + 256
    float acc0[RPB], acc1[RPB];
    #pragma unroll
    for (int r = 0; r < RPB; ++r) { acc0[r] = 0.f; acc1[r] = 0.f; }

    const float4* c0p = (const float4*)core + (size_t)tid * 128;
    const float4* c1p = (const float4*)core + (size_t)(tid + 256) * 128;

    #pragma unroll 1
    for (int k4 = 0; k4 < 128; ++k4) {
        float4 c0 = c0p[k4];
        float4 c1 = c1p[k4];
        #pragma unroll
        for (int r = 0; r < RPB; ++r) {
            float4 t = *(const float4*)&t3all[r][k4 << 2];
            acc0[r] = fmaf(t.w, c0.w, fmaf(t.z, c0.z, fmaf(t.y, c0.y, fmaf(t.x, c0.x, acc0[r]))));
            acc1[r] = fmaf(t.w, c1.w, fmaf(t.z, c1.z, fmaf(t.y, c1.y, fmaf(t.x, c1.x, acc1[r]))));
        }
    }

    // ---------------- Phase C: expand 2 rows per group ----------------
    const float alphav = alpha_p[0];
    float* t4g = scratch;            // [2][512]
    float* t5g = scratch + 1024;     // [2][1024]  t5[X][y][z] = X*64+y*8+z
    float* t6g = scratch + 3072;     // [2][2048]  t6[X][Y][z] = X*128+Y*8+z
    const int row = tid >> 7;        // 0/1
    const int t   = tid & 127;

    #pragma unroll
    for (int g = 0; g < 8; ++g) {
        __syncthreads();   // scratch reuse boundary
        t4g[tid]        = acc0[2 * g];
        t4g[256 + tid]  = acc1[2 * g];
        t4g[512 + tid]  = acc0[2 * g + 1];
        t4g[768 + tid]  = acc1[2 * g + 1];
        __syncthreads();
        // t5[X,y,z] = sum_x t4[x,y,z] * fo0[X,x]
        {
            const int yz = t & 63, xh = t >> 6;
            float a8[8] = {0,0,0,0,0,0,0,0};
            #pragma unroll
            for (int xx = 0; xx < 8; ++xx) {
                float v = t4g[row * 512 + xx * 64 + yz];
                #pragma unroll
                for (int xi = 0; xi < 8; ++xi)
                    a8[xi] += v * fac[3][(xh * 8 + xi) * 8 + xx];
            }
            #pragma unroll
            for (int xi = 0; xi < 8; ++xi)
                t5g[row * 1024 + (xh * 8 + xi) * 64 + yz] = a8[xi];
        }
        __syncthreads();
        // t6[X,Y,z] = sum_y t5[X,y,z] * fo1[Y,y]
        {
            const int X = t >> 3, z = t & 7;
            float a16[16] = {0,0,0,0,0,0,0,0,0,0,0,0,0,0,0,0};
            #pragma unroll
            for (int y = 0; y < 8; ++y) {
                float v = t5g[row * 1024 + X * 64 + y * 8 + z];
                #pragma unroll
                for (int Y = 0; Y < 16; ++Y) a16[Y] += v * fac[4][Y * 8 + y];
            }
            #pragma unroll
            for (int Y = 0; Y < 16; ++Y) t6g[row * 2048 + X * 128 + Y * 8 + z] = a16[Y];
        }
        __syncthreads();
        // out[X,Y,Z] = (sum_z t6[X,Y,z] * fo2[Z,z]) * pds * alpha + bias
        {
            const int n = n0 + 2 * g + row;
            float* orow = out + (size_t)n * D;
            #pragma unroll
            for (int h = 0; h < 2; ++h) {
                const int xy = t + h * 128;
                const int X = xy >> 4, Y = xy & 15;
                float a16[16] = {0,0,0,0,0,0,0,0,0,0,0,0,0,0,0,0};
                #pragma unroll
                for (int z = 0; z < 8; ++z) {
                    float v = t6g[row * 2048 + X * 128 + Y * 8 + z];
                    #pragma unroll
                    for (int Z = 0; Z < 16; ++Z) a16[Z] += v * fac[5][Z * 8 + z];
                }
                const int j0 = X * 256 + Y * 16;
                #pragma unroll
                for (int w = 0; w < 4; ++w) {
                    float4 pv = *(const float4*)&pds[j0 + w * 4];
                    float4 bv = *(const float4*)&bias[j0 + w * 4];
                    float4 ov;
                    ov.x = a16[w * 4 + 0] * pv.x * alphav + bv.x;
                    ov.y = a16[w * 4 + 1] * pv.y * alphav + bv.y;
                    ov.z = a16[w * 4 + 2] * pv.z * alphav + bv.z;
                    ov.w = a16[w * 4 + 3] * pv.w * alphav + bv.w;
                    *(float4*)&orow[j0 + w * 4] = ov;
                }
            }
        }
    }
}

extern "C" void kernel_launch(void* const* d_in, const int* in_sizes, int n_in,
                              void* d_out, int out_size, void* d_ws, size_t ws_size,
                              hipStream_t stream) {
    const float* x     = (const float*)d_in[0];
    const float* core  = (const float*)d_in[1];
    const float* fi0   = (const float*)d_in[2];
    const float* fi1   = (const float*)d_in[3];
    const float* fi2   = (const float*)d_in[4];
    const float* fo0   = (const float*)d_in[5];
    const float* fo1   = (const float*)d_in[6];
    const float* fo2   = (const float*)d_in[7];
    const float* pds   = (const float*)d_in[8];
    const float* alpha = (const float*)d_in[9];
    const float* bias  = (const float*)d_in[10];
    const int*   perm  = (const int*)d_in[11];
    float* outp = (float*)d_out;

    int* inv = (int*)d_ws;   // 4096 ints

    k_inv_perm<<<D / THREADS, THREADS, 0, stream>>>(perm, inv);
    k_tucker<<<NROWS / RPB, THREADS, 0, stream>>>(
        x, core, fi0, fi1, fi2, fo0, fo1, fo2, pds, alpha, bias, inv, outp);
}

// Round 2
// 316.248 us; speedup vs baseline: 1.4601x; 1.4601x over previous
//
#include <hip/hip_runtime.h>
#include <stdint.h>

#define NROWS 16384
#define D 4096

typedef __bf16 bf16x8 __attribute__((ext_vector_type(8)));
typedef float  f32x4  __attribute__((ext_vector_type(4)));

__device__ inline unsigned short f2bf(float f) {
    unsigned u = __float_as_uint(f);
    u += 0x7fffu + ((u >> 16) & 1u);
    return (unsigned short)(u >> 16);
}

// ---------------- setup: inverse permutation ----------------
__global__ __launch_bounds__(256) void k_inv_perm(const int* __restrict__ perm,
                                                  int* __restrict__ inv) {
    int d = blockIdx.x * blockDim.x + threadIdx.x;
    if (d < D) inv[perm[d]] = d;
}

// ---------------- Wco build: c1[X][y][z][pqr] = sum_x fo0[X,x] core[x,y,z,pqr]
__global__ __launch_bounds__(256) void k_b1(const float* __restrict__ core,
                                            const float* __restrict__ fo0,
                                            float* __restrict__ c1) {
    int g = blockIdx.x * 256 + threadIdx.x;      // 524288
    int pqr = g & 511, z = (g >> 9) & 7, y = (g >> 12) & 7, X = g >> 15;
    float s = 0.f;
    #pragma unroll
    for (int x = 0; x < 8; ++x)
        s += fo0[X * 8 + x] * core[x * 32768 + y * 4096 + z * 512 + pqr];
    c1[g] = s;
}

// c2[X][Y][z][pqr] = sum_y fo1[Y,y] c1[X,y,z,pqr]
__global__ __launch_bounds__(256) void k_b2(const float* __restrict__ c1,
                                            const float* __restrict__ fo1,
                                            float* __restrict__ c2) {
    int g = blockIdx.x * 256 + threadIdx.x;      // 1048576
    int pqr = g & 511, z = (g >> 9) & 7, Y = (g >> 12) & 15, X = g >> 16;
    float s = 0.f;
    #pragma unroll
    for (int y = 0; y < 8; ++y)
        s += fo1[Y * 8 + y] * c1[X * 32768 + y * 4096 + z * 512 + pqr];
    c2[g] = s;
}

// Wco_bf[n=XYZ][k=pqr] = sum_z fo2[Z,z] c2[X,Y,z,pqr]  (packed 2 bf16 / u32)
__global__ __launch_bounds__(256) void k_b3(const float* __restrict__ c2,
                                            const float* __restrict__ fo2,
                                            unsigned int* __restrict__ wco) {
    int g = blockIdx.x * 256 + threadIdx.x;      // 1048576
    int kp = g & 255, n = g >> 8;
    int X = n >> 8, Y = (n >> 4) & 15, Z = n & 15;
    float s0 = 0.f, s1 = 0.f;
    #pragma unroll
    for (int z = 0; z < 8; ++z) {
        float2 v = *(const float2*)&c2[X * 65536 + Y * 4096 + z * 512 + 2 * kp];
        float f = fo2[Z * 8 + z];
        s0 += f * v.x; s1 += f * v.y;
    }
    wco[g] = (unsigned)f2bf(s0) | ((unsigned)f2bf(s1) << 16);
}

// ---------------- input contraction: one row per block -> t3 bf16 ----------------
__global__ __launch_bounds__(256, 4) void k_t3(const float* __restrict__ x,
                                               const float* __restrict__ fi0,
                                               const float* __restrict__ fi1,
                                               const float* __restrict__ fi2,
                                               const int* __restrict__ inv,
                                               unsigned int* __restrict__ t3out) {
    __shared__ float xr[4096];    // 16 KB
    __shared__ float t1[2048];    //  8 KB
    __shared__ float t2[1024];    //  4 KB
    __shared__ float t3l[512];    //  2 KB

    const int tid = threadIdx.x;
    const int n = blockIdx.x;

    // coalesced row load + permuted scatter into LDS
    const float4* xrow = (const float4*)(x + (size_t)n * D);
    #pragma unroll
    for (int it = 0; it < 4; ++it) {
        float4 v = xrow[tid + it * 256];
        int4  iv = ((const int4*)inv)[tid + it * 256];
        xr[iv.x] = v.x; xr[iv.y] = v.y; xr[iv.z] = v.z; xr[iv.w] = v.w;
    }
    __syncthreads();

    // step 3: t1[p][bc] = sum_a xr[a*256+bc] * fi0[a,p]
    {
        float a8[8] = {0,0,0,0,0,0,0,0};
        #pragma unroll
        for (int a = 0; a < 16; ++a) {
            float v = xr[a * 256 + tid];
            #pragma unroll
            for (int p = 0; p < 8; ++p) a8[p] += v * fi0[a * 8 + p];
        }
        #pragma unroll
        for (int p = 0; p < 8; ++p) t1[p * 256 + tid] = a8[p];
    }
    __syncthreads();

    // step 4: t2[p][q][c] = sum_b t1[p][b*16+c] * fi1[b,q]   (thread: p,c,q-half)
    {
        const int p = tid >> 5, c = (tid >> 1) & 15, qh = tid & 1;
        float a4[4] = {0,0,0,0};
        #pragma unroll
        for (int b = 0; b < 16; ++b) {
            float v = t1[p * 256 + b * 16 + c];
            #pragma unroll
            for (int qi = 0; qi < 4; ++qi) a4[qi] += v * fi1[b * 8 + qh * 4 + qi];
        }
        #pragma unroll
        for (int qi = 0; qi < 4; ++qi) t2[p * 128 + (qh * 4 + qi) * 16 + c] = a4[qi];
    }
    __syncthreads();

    // step 5: t3[p][q][rr] = sum_c t2[p][q][c] * fi2[c,rr]   (thread: p,q,rr-quarter)
    {
        const int p = tid >> 5, q = (tid >> 2) & 7, rh = tid & 3;
        float a2[2] = {0,0};
        #pragma unroll
        for (int c = 0; c < 16; ++c) {
            float v = t2[p * 128 + q * 16 + c];
            #pragma unroll
            for (int ri = 0; ri < 2; ++ri) a2[ri] += v * fi2[c * 8 + rh * 2 + ri];
        }
        t3l[p * 64 + q * 8 + rh * 2 + 0] = a2[0];
        t3l[p * 64 + q * 8 + rh * 2 + 1] = a2[1];
    }
    __syncthreads();

    // pack to bf16 and store (coalesced u32)
    t3out[(size_t)n * 256 + tid] =
        (unsigned)f2bf(t3l[2 * tid]) | ((unsigned)f2bf(t3l[2 * tid + 1]) << 16);
}

// ---------------- GEMM: out[n][4096] = t3[n][512] @ Wco^T + epilogue ----------------
// 128x128 tile, BK=64, 4 waves (2x2 of 64x64), mfma_f32_16x16x32_bf16
__global__ __launch_bounds__(256, 2) void k_gemm(const __bf16* __restrict__ t3,
                                                 const __bf16* __restrict__ wco,
                                                 const float* __restrict__ pds,
                                                 const float* __restrict__ alphap,
                                                 const float* __restrict__ bias,
                                                 float* __restrict__ out) {
    __shared__ __bf16 lA[8192];   // [k4 0..7][row 0..127][8]  16 KB
    __shared__ __bf16 lB[8192];   // same for B               16 KB

    const int tid = threadIdx.x, lane = tid & 63, wv = tid >> 6;
    // bijective XCD swizzle (4096 % 8 == 0)
    const int bid = blockIdx.x;
    const int wg = (bid & 7) * 512 + (bid >> 3);
    const int m0 = (wg & 127) * 128;
    const int n0 = (wg >> 7) * 128;
    const int wm = wv >> 1, wn = wv & 1;
    const int l15 = lane & 15, l4 = lane >> 4;

    f32x4 acc[4][4] = {};

    for (int ks = 0; ks < 8; ++ks) {
        #pragma unroll
        for (int i = 0; i < 4; ++i) {
            const int u = i * 256 + wv * 64 + lane;
            const int r = u & 127, k4 = u >> 7;
            const __bf16* ga = t3 + (size_t)(m0 + r) * 512 + ks * 64 + k4 * 8;
            __builtin_amdgcn_global_load_lds(
                (const __attribute__((address_space(1))) void*)ga,
                (__attribute__((address_space(3))) void*)(lA + i * 2048 + wv * 512),
                16, 0, 0);
            const __bf16* gb = wco + (size_t)(n0 + r) * 512 + ks * 64 + k4 * 8;
            __builtin_amdgcn_global_load_lds(
                (const __attribute__((address_space(1))) void*)gb,
                (__attribute__((address_space(3))) void*)(lB + i * 2048 + wv * 512),
                16, 0, 0);
        }
        __syncthreads();
        #pragma unroll
        for (int kk = 0; kk < 2; ++kk) {
            const int k4f = kk * 4 + l4;
            bf16x8 af[4], bfr[4];
            #pragma unroll
            for (int mt = 0; mt < 4; ++mt)
                af[mt] = *(const bf16x8*)&lA[(k4f * 128 + wm * 64 + mt * 16 + l15) * 8];
            #pragma unroll
            for (int nt = 0; nt < 4; ++nt)
                bfr[nt] = *(const bf16x8*)&lB[(k4f * 128 + wn * 64 + nt * 16 + l15) * 8];
            #pragma unroll
            for (int mt = 0; mt < 4; ++mt)
                #pragma unroll
                for (int nt = 0; nt < 4; ++nt)
                    acc[mt][nt] = __builtin_amdgcn_mfma_f32_16x16x32_bf16(
                        af[mt], bfr[nt], acc[mt][nt], 0, 0, 0);
        }
        __syncthreads();
    }

    // epilogue: scale * alpha + bias, scattered fp32 stores (64B segments / 16 lanes)
    const float alpha = alphap[0];
    #pragma unroll
    for (int nt = 0; nt < 4; ++nt) {
        const int col = n0 + wn * 64 + nt * 16 + l15;
        const float pv = pds[col] * alpha;
        const float bv = bias[col];
        #pragma unroll
        for (int mt = 0; mt < 4; ++mt) {
            const int row = m0 + wm * 64 + mt * 16 + l4 * 4;
            #pragma unroll
            for (int j = 0; j < 4; ++j)
                out[(size_t)(row + j) * 4096 + col] = acc[mt][nt][j] * pv + bv;
        }
    }
}

extern "C" void kernel_launch(void* const* d_in, const int* in_sizes, int n_in,
                              void* d_out, int out_size, void* d_ws, size_t ws_size,
                              hipStream_t stream) {
    const float* x     = (const float*)d_in[0];
    const float* core  = (const float*)d_in[1];
    const float* fi0   = (const float*)d_in[2];
    const float* fi1   = (const float*)d_in[3];
    const float* fi2   = (const float*)d_in[4];
    const float* fo0   = (const float*)d_in[5];
    const float* fo1   = (const float*)d_in[6];
    const float* fo2   = (const float*)d_in[7];
    const float* pds   = (const float*)d_in[8];
    const float* alpha = (const float*)d_in[9];
    const float* bias  = (const float*)d_in[10];
    const int*   perm  = (const int*)d_in[11];
    float* outp = (float*)d_out;

    char* ws = (char*)d_ws;
    int*          inv  = (int*)(ws);                         // 16 KB
    float*        c1   = (float*)(ws + 16384);               // 2 MB
    float*        c2   = (float*)(ws + 16384 + 2097152);     // 4 MB
    unsigned int* wco  = (unsigned int*)(ws + 16384 + 2097152 + 4194304);   // 4 MB
    unsigned int* t3ws = (unsigned int*)(ws + 16384 + 2097152 + 8388608);   // 16 MB

    k_inv_perm<<<16, 256, 0, stream>>>(perm, inv);
    k_b1<<<2048, 256, 0, stream>>>(core, fo0, c1);
    k_b2<<<4096, 256, 0, stream>>>(c1, fo1, c2);
    k_b3<<<4096, 256, 0, stream>>>(c2, fo2, wco);
    k_t3<<<NROWS, 256, 0, stream>>>(x, fi0, fi1, fi2, inv, t3ws);
    k_gemm<<<4096, 256, 0, stream>>>((const __bf16*)t3ws, (const __bf16*)wco,
                                     pds, alpha, bias, outp);
}